// Round 10
// baseline (217.152 us; speedup 1.0000x reference)
//
#include <hip/hip_runtime.h>

// PDELoss fused — R10: continuous-streaming LDS-ring version (R9 hardened).
//
// Evidence through R8: every structure (register rolls, unrolls, LDS tile)
// pins at ~50-56us; L3-hot dispatches (hbm_bytes~0) are JUST AS SLOW, and all
// rounds converge to ~2.6-2.9 TB/s total delivered traffic (even R1's
// scratch-thrasher). Diagnosis: phase-separated memory (burst->stall->compute)
// caps in-flight bytes at ~4KB/CU -> Little's-law ceiling ~2.7 TB/s.
// R9/R10 keep the memory pipe ALWAYS busy: per-wave LDS ring buffers, 2 DMAs
// issued per iteration, counted s_waitcnt vmcnt(5) (never 0 until tail),
// no __syncthreads in the hot loop. Whole grid (1024 blocks = 4/CU at
// 37.2KB LDS) co-resident; waves live the entire kernel.
//
// R9 FAILED (container died twice). Fault audit found: rhs 16B/lane DMA
// overran the rhs allocation by 8B on the last row of the last image
// (OW=254, DMA covers 256 floats) -> likely page fault. R10 fixes:
//  (1) stage_rhs clamps staged rows to <= OH-2 (no overrun anywhere); the
//      one real row lost (OH-1, consumed only by the last strip) is carried
//      in registers preloaded BEFORE the vmcnt baseline (counting intact)
//      and substituted at emit via a wave-uniform select.
//  (2) pred-ring halo pads (floats 256..259/slot, read by lane63, never
//      DMA-written) are zeroed at startup -> no 0*NaN.
//  (3) extra sched_barrier(0) before the vmcnt(0) baseline.
//
// Wave = one (image, 16-row strip). Rings: pred 5 slots x 260 floats
// (256 data + 4 halo-pad), rhs 4 slots x 256 floats. DMA schedule
// (prologue p0..p4,r0,r1; iter K issues pred K+5 [K<=14], rhs K+2 [K<=13],
// order pinned by sched_barrier(0)): at iter K, vmcnt(N) with
// N = {K=0:4, 1..14:5, 15:4, 16:2, 17:0} guarantees pred rows <=K+2 and
// rhs row K-2 landed (index-verified, tight). All 36 DMAs ALWAYS issued
// with row-clamped addresses so counting is wave-uniform; garbage rows are
// masked by the existing gs/emit guards.

__device__ __forceinline__ void g2lds16(const float* g, float* l) {
    __builtin_amdgcn_global_load_lds(
        (const __attribute__((address_space(1))) void*)g,
        (__attribute__((address_space(3))) void*)l,
        16 /*bytes, literal*/, 0, 0);
}

__global__ __launch_bounds__(256)
void pde_loss_kernel(const float* __restrict__ pred,   // [B,256,256]
                     const float* __restrict__ rhs,    // [B,254,254]
                     const float* __restrict__ KL,     // [B,3,3]
                     const float* __restrict__ KD,     // [B,3,3]
                     const float* __restrict__ RR,     // [B,256,256] (col-only)
                     const float* __restrict__ ZZ,     // [B,256,256] (row-only)
                     float* __restrict__ partials)     // [gridDim.x]
{
    constexpr int H = 256, W = 256, OH = 254, OW = 254;
    constexpr int PR = 5, PSTR = 260;                 // pred ring
    constexpr int RS = 4, RSTR = 256;                 // rhs ring
    constexpr int WREG = PR * PSTR + RS * RSTR;       // 2324 floats / wave
    __shared__ float lds[4 * WREG];                   // 37184 B
    __shared__ float wsum[4];

    const int tid = threadIdx.x;
    const int l   = tid & 63;          // lane
    const int wv  = tid >> 6;          // wave in block (0..3)
    const int b   = blockIdx.x >> 2;   // image (1024 blocks, 4 per image)
    const int strip = (blockIdx.x & 3) * 4 + wv;   // 16 strips of 16 rows
    const int o0 = strip * 16;
    const int o1 = (o0 + 16 < OH) ? (o0 + 16) : OH;   // last strip: 14 rows
    const int c0 = 4 * l;

    const size_t ib = (size_t)b * H * W;
    const float* predb = pred + ib;
    const float* rhsb  = rhs + (size_t)b * OH * OW;
    float* wls = &lds[wv * WREG];      // wave-private ring region

    // zero pred-ring halo pads (floats 256..259 of each pred slot; lane63's
    // halo float2 reads them; DMA never writes them)
    if (l < PR)
        *(float4*)(wls + l * PSTR + 256) = make_float4(0.f, 0.f, 0.f, 0.f);

    // ---- setup loads + per-column folded coefficients (all consumed) ----
    const float hr  = RR[ib + W + 2] - RR[ib + W + 1];
    const float hz  = ZZ[ib + 2 * W + 1] - ZZ[ib + W + 1];
    const float hr2 = hr * hr, hz2 = hz * hz;
    const float s   = -2.0f * (hr2 + hz2) / (hr2 * hz2);
    float4 invr;
    invr.x = 1.0f / RR[ib + W + (c0 + 1)];
    invr.y = 1.0f / RR[ib + W + (c0 + 2)];
    invr.z = 1.0f / RR[ib + W + (c0 + 3)];
    invr.w = 1.0f / RR[ib + W + ((c0 + 4 < W) ? (c0 + 4) : (W - 1))];
    const bool lastl = (l == 63);
    float4 c4[9];
#pragma unroll
    for (int t = 0; t < 9; ++t) {
        const float a = KL[b * 9 + t] * s, d = KD[b * 9 + t] * s;
        c4[t].x = fmaf(d, invr.x, a);
        c4[t].y = fmaf(d, invr.y, a);
        c4[t].z = lastl ? 0.f : fmaf(d, invr.z, a);   // cols 254/255 dead
        c4[t].w = lastl ? 0.f : fmaf(d, invr.w, a);
    }
    const float m23 = (c0 + 2 < OW) ? 1.f : 0.f;   // emit cols c0+2,c0+3 valid
    const float m0  = (l > 0) ? 1.f : 0.f;         // left-halo validity

    // last-row rhs (row OH-1) via registers: staging clamps rows to OH-2 so
    // the 16B/lane DMA can never overrun the rhs allocation (R9 crash fix).
    // Only the last strip consumes row OH-1. Loads sit above the baseline.
    float2 rl0 = make_float2(0.f, 0.f), rl1 = make_float2(0.f, 0.f);
    if (o1 == OH) {
        const float* rr = rhsb + (size_t)(OH - 1) * OW + c0;
        rl0 = *(const float2*)rr;
        if (c0 + 2 < OW) rl1 = *(const float2*)(rr + 2);
    }

    // DMA issue helpers — ALWAYS issue (clamped row), so vmcnt counting is
    // uniform across waves. Garbage rows masked by gs/emit guards.
    auto stage_pred = [&](int j) {                  // local row j = 0..19
        int gr = o0 - 1 + j;
        gr = (gr < 0) ? 0 : ((gr > H - 1) ? H - 1 : gr);
        g2lds16(predb + (size_t)gr * W + c0, wls + (j % PR) * PSTR);
    };
    auto stage_rhs = [&](int j) {                   // local row j = 0..15
        int gr = o0 + j;
        gr = (gr > OH - 2) ? (OH - 2) : gr;         // never touches row OH-1
        g2lds16(rhsb + (size_t)gr * OW + c0, wls + PR * PSTR + (j % RS) * RSTR);
    };

    // clean vmcnt baseline, then prologue DMAs in pinned order
    __builtin_amdgcn_sched_barrier(0);
    asm volatile("s_waitcnt vmcnt(0)" ::: "memory");
    stage_pred(0); __builtin_amdgcn_sched_barrier(0);
    stage_pred(1); __builtin_amdgcn_sched_barrier(0);
    stage_pred(2); __builtin_amdgcn_sched_barrier(0);
    stage_pred(3); __builtin_amdgcn_sched_barrier(0);
    stage_pred(4); __builtin_amdgcn_sched_barrier(0);
    stage_rhs(0);  __builtin_amdgcn_sched_barrier(0);
    stage_rhs(1);  __builtin_amdgcn_sched_barrier(0);

#define SROW(P, Hh, t0, t1, t2)                                               \
    gs.x = fmaf(P.x, c4[t0].x, fmaf(P.y, c4[t1].x, fmaf(P.z,  c4[t2].x, gs.x))); \
    gs.y = fmaf(P.y, c4[t0].y, fmaf(P.z, c4[t1].y, fmaf(P.w,  c4[t2].y, gs.y))); \
    gs.z = fmaf(P.z, c4[t0].z, fmaf(P.w, c4[t1].z, fmaf(Hh.x, c4[t2].z, gs.z))); \
    gs.w = fmaf(P.w, c4[t0].w, fmaf(Hh.x, c4[t1].w, fmaf(Hh.y, c4[t2].w, gs.w)));

    float4 p0, p1, p2;          // window rows K, K+1, K+2
    float2 h0, h1, h2;          // their right-halos (cols c0+4,c0+5)
    float4 ghm2 = make_float4(0.f, 0.f, 0.f, 0.f);
    float4 ghm1 = make_float4(0.f, 0.f, 0.f, 0.f);
    float acc = 0.0f;

#pragma unroll
    for (int K = 0; K < 18; ++K) {
        // (a) counted wait: pred rows <=K+2 and rhs row K-2 are landed
        if (K == 0 || K == 15)  asm volatile("s_waitcnt vmcnt(4)" ::: "memory");
        else if (K <= 14)       asm volatile("s_waitcnt vmcnt(5)" ::: "memory");
        else if (K == 16)       asm volatile("s_waitcnt vmcnt(2)" ::: "memory");
        else                    asm volatile("s_waitcnt vmcnt(0)" ::: "memory");

        // (b) window reads from the pred ring
        if (K == 0) {
            p0 = *(const float4*)(wls + 0 * PSTR + c0);
            h0 = *(const float2*)(wls + 0 * PSTR + c0 + 4);
            p1 = *(const float4*)(wls + 1 * PSTR + c0);
            h1 = *(const float2*)(wls + 1 * PSTR + c0 + 4);
        }
        {
            const int sl = (K + 2) % PR;
            p2 = *(const float4*)(wls + sl * PSTR + c0);
            h2 = *(const float2*)(wls + sl * PSTR + c0 + 4);
        }

        // (c) GS row g (zero outside [0,OH): SAME padding)
        const int g = o0 - 1 + K;
        float4 gs = make_float4(0.f, 0.f, 0.f, 0.f);
        if ((unsigned)g < (unsigned)OH) {
            SROW(p0, h0, 0, 1, 2)
            SROW(p1, h1, 3, 4, 5)
            SROW(p2, h2, 6, 7, 8)
        }

        // horizontal [1,2,1]
        const float up = __shfl(gs.w, l - 1, 64) * m0;  // lane0 -> 0
        const float dn = __shfl(gs.x, l + 1, 64);       // lane63 dead via m23
        float4 gh;
        gh.x = fmaf(2.f, gs.x, up   + gs.y);
        gh.y = fmaf(2.f, gs.y, gs.x + gs.z);
        gh.z = fmaf(2.f, gs.z, gs.y + gs.w);
        gh.w = fmaf(2.f, gs.w, gs.z + dn);

        // vertical [1,2,1]/16: emit output row i = g-1, MSE accumulate
        if (K >= 2) {
            const int i = o0 + K - 2;
            if (i < o1) {                                // uniform guard
                const float* rr = wls + PR * PSTR + ((K - 2) % RS) * RSTR + c0;
                float4 rv = *(const float4*)rr;
                if (i == OH - 1)                         // uniform: last strip
                    rv = make_float4(rl0.x, rl0.y, rl1.x, rl1.y);
                const float smx = (ghm2.x + 2.f * ghm1.x + gh.x) * 0.0625f;
                const float smy = (ghm2.y + 2.f * ghm1.y + gh.y) * 0.0625f;
                const float smz = (ghm2.z + 2.f * ghm1.z + gh.z) * 0.0625f;
                const float smw = (ghm2.w + 2.f * ghm1.w + gh.w) * 0.0625f;
                const float dx = smx - rv.x;
                const float dy = smy - rv.y;
                const float dz = (smz - rv.z) * m23;
                const float dw = (smw - rv.w) * m23;
                acc = fmaf(dx, dx, acc);
                acc = fmaf(dy, dy, acc);
                acc = fmaf(dz, dz, acc);
                acc = fmaf(dw, dw, acc);
            }
        }

        // (d) rotate window (SSA under full unroll)
        p0 = p1; p1 = p2; h0 = h1; h1 = h2;
        ghm2 = ghm1; ghm1 = gh;

        // (e) issue next DMAs, order pinned: pred first, then rhs
        if (K <= 14) stage_pred(K + 5);
        __builtin_amdgcn_sched_barrier(0);
        if (K <= 13) stage_rhs(K + 2);
        __builtin_amdgcn_sched_barrier(0);
    }
#undef SROW

    // wave reduce -> block partial -> one contention-free store per block
#pragma unroll
    for (int off = 32; off > 0; off >>= 1)
        acc += __shfl_down(acc, off, 64);
    if (l == 0) wsum[wv] = acc;
    __syncthreads();
    if (tid == 0)
        partials[blockIdx.x] = (wsum[0] + wsum[1]) + (wsum[2] + wsum[3]);
}

// Second stage: reduce N partials -> out (single block). Applies inv_n, so no
// memset dispatch is needed anywhere.
__global__ __launch_bounds__(256)
void reduce_kernel(const float* __restrict__ partials, float* __restrict__ out,
                   int n, float inv_n)
{
    const int tid = threadIdx.x;
    float a = 0.0f;
    for (int i = tid; i < n; i += 256) a += partials[i];
#pragma unroll
    for (int off = 32; off > 0; off >>= 1)
        a += __shfl_down(a, off, 64);
    __shared__ float w[4];
    if ((tid & 63) == 0) w[tid >> 6] = a;
    __syncthreads();
    if (tid == 0) out[0] = ((w[0] + w[1]) + (w[2] + w[3])) * inv_n;
}

extern "C" void kernel_launch(void* const* d_in, const int* in_sizes, int n_in,
                              void* d_out, int out_size, void* d_ws, size_t ws_size,
                              hipStream_t stream) {
    const float* pred = (const float*)d_in[0];
    const float* rhs  = (const float*)d_in[1];
    const float* KL   = (const float*)d_in[2];
    const float* KD   = (const float*)d_in[3];
    const float* RR   = (const float*)d_in[4];
    const float* ZZ   = (const float*)d_in[5];
    // d_in[6] = Gauss kernel [[1,2,1],[2,4,2],[1,2,1]]/16 — hardcoded, separable
    float* out = (float*)d_out;

    const int B = in_sizes[2] / 9;   // 256
    const int nblocks = B * 4;       // 4-wave blocks, 4 strips each; 4 blocks/CU
    const float inv_n = 1.0f / ((float)B * 254.0f * 254.0f);

    float* partials = (float*)d_ws;  // nblocks floats
    pde_loss_kernel<<<dim3(nblocks), dim3(256), 0, stream>>>(
        pred, rhs, KL, KD, RR, ZZ, partials);
    reduce_kernel<<<dim3(1), dim3(256), 0, stream>>>(partials, out, nblocks, inv_n);
}

// Round 11
// 214.311 us; speedup vs baseline: 1.0133x; 1.0133x over previous
//
#include <hip/hip_runtime.h>

// PDELoss fused, wave-autonomous version — R11: R5 structure, 16-row strips.
//
// Model (validated across R0-R10): per-CU global READ service rate is
// ~5-6.4 B/cy — every design (register rolls, unrolls, LDS tile, DMA ring,
// counted-vmcnt stream) converges to it, and speed ranking == serviced-B/cy
// ranking (R5's 6.4 was fastest). The m13 6.3 TB/s "copy ceiling" is
// read+write; pure-read ceiling ≈ half => we are AT the read roofline, which
// is why L3-hot runs are equally slow and VALU/occupancy idle. Remaining
// levers: request fewer bytes; keep R5's best-in-class service efficiency.
//
// R11 = R5 verbatim except strip 8->16 rows (halo re-read 1.25x -> 1.125x =
// -7% requested bytes; setup per wave halved; 18/16 iterations still even so
// the proven 2-row body is untouched), grid 512 blocks x 512 threads.
// Pre-committed read: >=49us => read-service ceiling binding => ROOFLINE.
//
// History: R1 grid-fill null; R2 launch_bounds(256,8) VGPR-capped -> spill;
// R4 atomic-storm removal 65->54; R5 2-row-body ILP 54->50; R6/R7
// register-MLP failed (compiler sinks loads, VGPR pinned 80); R8 LDS tile
// neutral; R9 rhs-DMA 8B overrun crashed container; R10 counted-vmcnt ring
// neutral (16% VALU) -> concurrency never the limit.

__global__ __launch_bounds__(512, 1)
void pde_loss_kernel(const float* __restrict__ pred,   // [B,256,256]
                     const float* __restrict__ rhs,    // [B,254,254]
                     const float* __restrict__ KL,     // [B,3,3]
                     const float* __restrict__ KD,     // [B,3,3]
                     const float* __restrict__ RR,     // [B,256,256] (col-only)
                     const float* __restrict__ ZZ,     // [B,256,256] (row-only)
                     float* __restrict__ partials)     // [gridDim.x]
{
    constexpr int H = 256, W = 256, OH = 254, OW = 254, SR = 16;
    const int tid = threadIdx.x;
    const int l   = tid & 63;          // lane
    const int wv  = tid >> 6;          // wave in block (0..7)
    const int b   = blockIdx.x >> 1;   // image (512 blocks, 2 per image)
    const int strip = (blockIdx.x & 1) * 8 + wv;   // 16 strips of 16 rows
    const int o0 = strip * SR;
    const int o1 = (o0 + SR < OH) ? (o0 + SR) : OH;   // last strip: 14 rows

    const size_t ib = (size_t)b * H * W;
    const float* predb = pred + ib;
    const float* rhsb  = rhs + (size_t)b * OH * OW;

    const float hr  = RR[ib + W + 2] - RR[ib + W + 1];
    const float hz  = ZZ[ib + 2 * W + 1] - ZZ[ib + W + 1];
    const float hr2 = hr * hr, hz2 = hz * hz;
    const float s   = -2.0f * (hr2 + hz2) / (hr2 * hz2);

    // Per-column folded coefficients over owned cols c0..c0+3.
    // Lane 63's .z/.w zeroed here: kills gs.z/gs.w for cols 254/255 forever
    // (also makes lane0's left-halo-from-lane63 read a guaranteed 0).
    const int c0 = 4 * l;
    float4 c4[9];
    {
        float4 invr;
        invr.x = 1.0f / RR[ib + W + (c0 + 1)];
        invr.y = 1.0f / RR[ib + W + (c0 + 2)];
        invr.z = 1.0f / RR[ib + W + (c0 + 3)];
        invr.w = 1.0f / RR[ib + W + ((c0 + 4 < W) ? (c0 + 4) : (W - 1))];
        const float* kl = KL + b * 9;
        const float* kd = KD + b * 9;
        const bool last = (l == 63);
#pragma unroll
        for (int t = 0; t < 9; ++t) {
            const float a = kl[t] * s, d = kd[t] * s;
            c4[t].x = fmaf(d, invr.x, a);
            c4[t].y = fmaf(d, invr.y, a);
            c4[t].z = last ? 0.f : fmaf(d, invr.z, a);
            c4[t].w = last ? 0.f : fmaf(d, invr.w, a);
        }
    }
    const float m23 = (c0 + 2 < OW) ? 1.f : 0.f;  // cols c0+2,c0+3 in range
    const float m0  = (l > 0) ? 1.f : 0.f;        // left-halo validity

    const int g0 = o0 - 1;
    const int rowlim = (o1 + 2 <= H - 1) ? (o1 + 2) : (H - 1); // last pred row needed&valid

    // Prologue: window rows g0, g0+1, g0+2 and their right-halos
    float4 p0 = make_float4(0.f, 0.f, 0.f, 0.f), p1, p2;
    if (g0 >= 0) p0 = *(const float4*)(predb + (size_t)g0 * W + c0);
    p1 = *(const float4*)(predb + (size_t)(g0 + 1) * W + c0);
    p2 = *(const float4*)(predb + (size_t)(g0 + 2) * W + c0);
    float h0x = __shfl(p0.x, l + 1, 64), h0y = __shfl(p0.y, l + 1, 64);
    float h1x = __shfl(p1.x, l + 1, 64), h1y = __shfl(p1.y, l + 1, 64);

    float4 ghA = make_float4(0.f, 0.f, 0.f, 0.f);   // gh row g-2
    float4 ghB = make_float4(0.f, 0.f, 0.f, 0.f);   // gh row g-1
    float2 rc0 = make_float2(0.f, 0.f), rc1 = make_float2(0.f, 0.f); // rhs row g-1
    float acc = 0.0f;

#define ROWC(gsv, p, nx, ny, t0)                                                  \
    gsv.x = fmaf(p.x, c4[t0].x, fmaf(p.y, c4[t0+1].x, fmaf(p.z, c4[t0+2].x, gsv.x))); \
    gsv.y = fmaf(p.y, c4[t0].y, fmaf(p.z, c4[t0+1].y, fmaf(p.w, c4[t0+2].y, gsv.y))); \
    gsv.z = fmaf(p.z, c4[t0].z, fmaf(p.w, c4[t0+1].z, fmaf(nx,  c4[t0+2].z, gsv.z))); \
    gsv.w = fmaf(p.w, c4[t0].w, fmaf(nx,  c4[t0+1].w, fmaf(ny,  c4[t0+2].w, gsv.w)));

    // Body covers output rows (g, g+1). Iteration count o1-g0+1 is 18 or 16:
    // always even, no tail.
    for (int g = g0; g < o1; g += 2) {
        // ---- body-top loads: pred rows g+3,g+4 ; rhs rows g,g+1 ----
        float4 pr3 = make_float4(0.f, 0.f, 0.f, 0.f);
        float4 pr4 = make_float4(0.f, 0.f, 0.f, 0.f);
        if (g + 3 <= rowlim) pr3 = *(const float4*)(predb + (size_t)(g + 3) * W + c0);
        if (g + 4 <= rowlim) pr4 = *(const float4*)(predb + (size_t)(g + 4) * W + c0);
        float2 rA0 = make_float2(0.f, 0.f), rA1 = make_float2(0.f, 0.f);
        float2 rB0 = make_float2(0.f, 0.f), rB1 = make_float2(0.f, 0.f);
        if (g >= o0 && g < o1) {
            const float* rr = rhsb + (size_t)g * OW + c0;
            rA0 = *(const float2*)rr;
            if (c0 + 2 < OW) rA1 = *(const float2*)(rr + 2);
        }
        if (g + 1 >= o0 && g + 1 < o1) {
            const float* rr = rhsb + (size_t)(g + 1) * OW + c0;
            rB0 = *(const float2*)rr;
            if (c0 + 2 < OW) rB1 = *(const float2*)(rr + 2);
        }

        // ---- phase A: GS_ope row g (rows g..g+2 = p0,p1,p2) ----
        const float h2x = __shfl(p2.x, l + 1, 64);
        const float h2y = __shfl(p2.y, l + 1, 64);
        float4 gs = make_float4(0.f, 0.f, 0.f, 0.f);
        if ((unsigned)g < (unsigned)OH) {
            ROWC(gs, p0, h0x, h0y, 0)
            ROWC(gs, p1, h1x, h1y, 3)
            ROWC(gs, p2, h2x, h2y, 6)
        }
        const float upA = __shfl(gs.w, l - 1, 64) * m0;
        const float dnA = __shfl(gs.x, l + 1, 64);   // lane63: dead via m23
        float4 ghC;
        ghC.x = fmaf(2.f, gs.x, upA  + gs.y);
        ghC.y = fmaf(2.f, gs.y, gs.x + gs.z);
        ghC.z = fmaf(2.f, gs.z, gs.y + gs.w);
        ghC.w = fmaf(2.f, gs.w, gs.z + dnA);
        if (g - 1 >= o0) {      // emit row g-1 (g-1 < o1 structurally)
            const float smx = (ghA.x + 2.f * ghB.x + ghC.x) * 0.0625f;
            const float smy = (ghA.y + 2.f * ghB.y + ghC.y) * 0.0625f;
            const float smz = (ghA.z + 2.f * ghB.z + ghC.z) * 0.0625f;
            const float smw = (ghA.w + 2.f * ghB.w + ghC.w) * 0.0625f;
            const float dx = smx - rc0.x;
            const float dy = smy - rc0.y;
            const float dz = (smz - rc1.x) * m23;
            const float dw = (smw - rc1.y) * m23;
            acc = fmaf(dx, dx, acc);
            acc = fmaf(dy, dy, acc);
            acc = fmaf(dz, dz, acc);
            acc = fmaf(dw, dw, acc);
        }

        // ---- phase B: GS_ope row g+1 (rows g+1..g+3 = p1,p2,pr3) ----
        const float h3x = __shfl(pr3.x, l + 1, 64);
        const float h3y = __shfl(pr3.y, l + 1, 64);
        float4 gt = make_float4(0.f, 0.f, 0.f, 0.f);
        if ((unsigned)(g + 1) < (unsigned)OH) {
            ROWC(gt, p1, h1x, h1y, 0)
            ROWC(gt, p2, h2x, h2y, 3)
            ROWC(gt, pr3, h3x, h3y, 6)
        }
        const float upB = __shfl(gt.w, l - 1, 64) * m0;
        const float dnB = __shfl(gt.x, l + 1, 64);
        float4 ghD;
        ghD.x = fmaf(2.f, gt.x, upB  + gt.y);
        ghD.y = fmaf(2.f, gt.y, gt.x + gt.z);
        ghD.z = fmaf(2.f, gt.z, gt.y + gt.w);
        ghD.w = fmaf(2.f, gt.w, gt.z + dnB);
        if (g >= o0) {          // emit row g (g < o1 from loop bound)
            const float smx = (ghB.x + 2.f * ghC.x + ghD.x) * 0.0625f;
            const float smy = (ghB.y + 2.f * ghC.y + ghD.y) * 0.0625f;
            const float smz = (ghB.z + 2.f * ghC.z + ghD.z) * 0.0625f;
            const float smw = (ghB.w + 2.f * ghC.w + ghD.w) * 0.0625f;
            const float dx = smx - rA0.x;
            const float dy = smy - rA0.y;
            const float dz = (smz - rA1.x) * m23;
            const float dw = (smw - rA1.y) * m23;
            acc = fmaf(dx, dx, acc);
            acc = fmaf(dy, dy, acc);
            acc = fmaf(dz, dz, acc);
            acc = fmaf(dw, dw, acc);
        }

        // ---- rotate (renaming, not data movement after unroll) ----
        p0 = p2; p1 = pr3; p2 = pr4;
        h0x = h2x; h0y = h2y; h1x = h3x; h1y = h3y;
        ghA = ghC; ghB = ghD;
        rc0 = rB0; rc1 = rB1;
    }
#undef ROWC

    // wave reduce -> block partial -> ONE contention-free store per block
#pragma unroll
    for (int off = 32; off > 0; off >>= 1)
        acc += __shfl_down(acc, off, 64);
    __shared__ float wsum[8];
    if (l == 0) wsum[wv] = acc;
    __syncthreads();
    if (tid == 0) {
        float t = 0.f;
#pragma unroll
        for (int k = 0; k < 8; ++k) t += wsum[k];
        partials[blockIdx.x] = t;
    }
}

// Second stage: reduce N partials -> out (single block). Applies inv_n, so no
// memset dispatch is needed anywhere.
__global__ __launch_bounds__(256)
void reduce_kernel(const float* __restrict__ partials, float* __restrict__ out,
                   int n, float inv_n)
{
    const int tid = threadIdx.x;
    float a = 0.0f;
    for (int i = tid; i < n; i += 256) a += partials[i];
#pragma unroll
    for (int off = 32; off > 0; off >>= 1)
        a += __shfl_down(a, off, 64);
    __shared__ float w[4];
    if ((tid & 63) == 0) w[tid >> 6] = a;
    __syncthreads();
    if (tid == 0) out[0] = ((w[0] + w[1]) + (w[2] + w[3])) * inv_n;
}

extern "C" void kernel_launch(void* const* d_in, const int* in_sizes, int n_in,
                              void* d_out, int out_size, void* d_ws, size_t ws_size,
                              hipStream_t stream) {
    const float* pred = (const float*)d_in[0];
    const float* rhs  = (const float*)d_in[1];
    const float* KL   = (const float*)d_in[2];
    const float* KD   = (const float*)d_in[3];
    const float* RR   = (const float*)d_in[4];
    const float* ZZ   = (const float*)d_in[5];
    // d_in[6] = Gauss kernel [[1,2,1],[2,4,2],[1,2,1]]/16 — hardcoded, separable
    float* out = (float*)d_out;

    const int B = in_sizes[2] / 9;   // 256
    const int nblocks = B * 2;       // 512-thread blocks, 8 strips of 16 rows
    const float inv_n = 1.0f / ((float)B * 254.0f * 254.0f);

    float* partials = (float*)d_ws;  // nblocks floats
    pde_loss_kernel<<<dim3(nblocks), dim3(512), 0, stream>>>(
        pred, rhs, KL, KD, RR, ZZ, partials);
    reduce_kernel<<<dim3(1), dim3(256), 0, stream>>>(partials, out, nblocks, inv_n);
}